// Round 4
// baseline (18581.610 us; speedup 1.0000x reference)
//
#include <hip/hip_runtime.h>
#include <cstdint>

#define T_DIM 512
#define B_DIM 256
#define F_DIM 513
#define DX    256
#define H_DIM 128
#define G4    512
#define Z_DIM 16
#define ZG_D  32
#define DZX_D 128
#define M_ROWS (B_DIM * T_DIM)   // 131072

__device__ __forceinline__ float fast_tanh(float x) {
    return 1.0f - 2.0f / (__expf(2.0f * x) + 1.0f);
}
__device__ __forceinline__ float fast_sig(float x) {
    return 1.0f / (1.0f + __expf(-x));
}

__global__ void bias_comb_kernel(const float* __restrict__ a,
                                 const float* __restrict__ b,
                                 float* __restrict__ c) {
    int i = threadIdx.x;
    if (i < G4) c[i] = a[i] + b[i];
}

// Generic tiled fp32 GEMM:  C[m,n] = act(sum_k A[m,k] * W[n,k] + bias[n])
// 128x128 tile, 256 threads, 8x8 per thread in a 2x2-of-4 split layout.
// Round-5: register-staged double buffer. Round-3 counters: VALUBusy 38%,
// HBM 6%, occupancy 31% -> latency-bound on the sync->load->sync->compute
// serialization. Now tile k+1's global loads issue BEFORE tile k's FMA
// phase (unconditional, clamped index so the compiler can't sink them into
// the conditional commit); LDS write happens after the post-compute barrier.
// ACT: 0 none, 1 tanh, 2 exp
// AMODE: 0 contiguous row-major [M,K], 1 x-gather A[m,k]=x[b,k,t], m=b*T+t
// CMODE: 0 contiguous [M,N] (N%128==0), 1 transposed out[b,n,t] via LDS
//        re-tile (coalesced 512B row stores), n<N guard
// GUARD: scalar+bounds-guarded W loads (K edge or N edge)
template<int ACT, int AMODE, int CMODE, bool GUARD>
__global__ __launch_bounds__(256, 3) void gemm_kernel(
    const float* __restrict__ A, const float* __restrict__ W,
    const float* __restrict__ bias, float* __restrict__ C,
    int M, int N, int K)
{
    __shared__ float As[16][136];
    __shared__ float Bs[16][136];
    const int tid = threadIdx.x;
    const int m0 = blockIdx.y * 128;
    const int n0 = blockIdx.x * 128;
    const int tm = tid >> 4;   // 0..15
    const int tn = tid & 15;   // 0..15
    float acc[8][8] = {};
    const int kTiles = (K + 15) >> 4;

    float sa[8], sb[8];

    // stage: global -> registers for tile kt_
    auto stage = [&](int kt_) {
        const int k0 = kt_ << 4;
        if (AMODE == 0) {
            const int m  = tid >> 1;        // 0..127
            const int kh = tid & 1;         // 0..1
            const float* ap = &A[(size_t)(m0 + m) * K + k0 + kh * 8];
            const float4 v0 = *(const float4*)(ap);
            const float4 v1 = *(const float4*)(ap + 4);
            sa[0] = v0.x; sa[1] = v0.y; sa[2] = v0.z; sa[3] = v0.w;
            sa[4] = v1.x; sa[5] = v1.y; sa[6] = v1.z; sa[7] = v1.w;
        } else {
            const int m  = tid & 127;       // lane-consecutive m -> t-contiguous
            const int kh = tid >> 7;        // 0..1
            const int mg = m0 + m;
            const int bb = mg >> 9;         // /T
            const int tt = mg & 511;        // %T
            const size_t base = (size_t)bb * (F_DIM * T_DIM) + tt;
            #pragma unroll
            for (int j = 0; j < 8; ++j) {
                const int k = k0 + kh * 8 + j;
                sa[j] = (k < K) ? A[base + (size_t)k * T_DIM] : 0.0f;
            }
        }
        {
            const int n  = tid >> 1;        // 0..127
            const int kh = tid & 1;
            const int ng = n0 + n;
            if (!GUARD) {
                const float* wp = &W[(size_t)ng * K + k0 + kh * 8];
                const float4 v0 = *(const float4*)(wp);
                const float4 v1 = *(const float4*)(wp + 4);
                sb[0] = v0.x; sb[1] = v0.y; sb[2] = v0.z; sb[3] = v0.w;
                sb[4] = v1.x; sb[5] = v1.y; sb[6] = v1.z; sb[7] = v1.w;
            } else {
                #pragma unroll
                for (int j = 0; j < 8; ++j) {
                    const int k = k0 + kh * 8 + j;
                    float v = 0.0f;
                    if (ng < N && k < K) v = W[(size_t)ng * K + k];
                    sb[j] = v;
                }
            }
        }
    };
    // commit: registers -> LDS
    auto commit = [&]() {
        {
            const int m  = (AMODE == 0) ? (tid >> 1) : (tid & 127);
            const int kh = (AMODE == 0) ? (tid & 1)  : (tid >> 7);
            #pragma unroll
            for (int j = 0; j < 8; ++j) As[kh * 8 + j][m] = sa[j];
        }
        {
            const int n  = tid >> 1;
            const int kh = tid & 1;
            #pragma unroll
            for (int j = 0; j < 8; ++j) Bs[kh * 8 + j][n] = sb[j];
        }
    };

    stage(0);
    commit();
    __syncthreads();
    for (int kt = 0; kt < kTiles; ++kt) {
        const bool more = (kt + 1 < kTiles);
        stage(more ? kt + 1 : kt);   // prefetch next tile (clamped re-read on last)
        #pragma unroll
        for (int kk = 0; kk < 16; ++kk) {
            const float4 a0 = *(const float4*)&As[kk][tm * 4];
            const float4 a1 = *(const float4*)&As[kk][tm * 4 + 64];
            const float4 b0 = *(const float4*)&Bs[kk][tn * 4];
            const float4 b1 = *(const float4*)&Bs[kk][tn * 4 + 64];
            const float a[8] = { a0.x, a0.y, a0.z, a0.w, a1.x, a1.y, a1.z, a1.w };
            const float b[8] = { b0.x, b0.y, b0.z, b0.w, b1.x, b1.y, b1.z, b1.w };
            #pragma unroll
            for (int i = 0; i < 8; ++i)
                #pragma unroll
                for (int j = 0; j < 8; ++j)
                    acc[i][j] += a[i] * b[j];
        }
        __syncthreads();
        if (more) commit();
        __syncthreads();
    }
    // ---- epilogue ----
    if (CMODE == 0) {
        #pragma unroll
        for (int i = 0; i < 8; ++i) {
            const int m = m0 + ((i < 4) ? (tm * 4 + i) : (tm * 4 + 64 + (i - 4)));
            float r0[4], r1[4];
            #pragma unroll
            for (int j = 0; j < 4; ++j) {
                const int na = n0 + tn * 4 + j;
                float v = acc[i][j] + bias[na];
                if (ACT == 1) v = fast_tanh(v);
                else if (ACT == 2) v = __expf(v);
                r0[j] = v;
                const int nb = n0 + 64 + tn * 4 + j;
                float u = acc[i][j + 4] + bias[nb];
                if (ACT == 1) u = fast_tanh(u);
                else if (ACT == 2) u = __expf(u);
                r1[j] = u;
            }
            *(float4*)&C[(size_t)m * N + n0 + tn * 4]      = make_float4(r0[0], r0[1], r0[2], r0[3]);
            *(float4*)&C[(size_t)m * N + n0 + 64 + tn * 4] = make_float4(r1[0], r1[1], r1[2], r1[3]);
        }
    } else {
        // Transposed out[b,n,t]: re-tile through LDS in 16-n-row chunks so
        // stores are 512B-contiguous rows (was a 16B/lane scatter).
        const int bb  = m0 >> 9;      // m-block lies in one b (m0%512 + 127 < 512)
        const int tt0 = m0 & 511;
        float* Cb = C + (size_t)bb * (F_DIM * T_DIM) + tt0;
        #pragma unroll
        for (int chunk = 0; chunk < 8; ++chunk) {
            __syncthreads();
            #pragma unroll
            for (int j = 0; j < 8; ++j) {
                const int ln = (j < 4) ? (tn * 4 + j) : (64 + tn * 4 + (j - 4));
                if ((ln >> 4) == chunk) {
                    const int n = n0 + ln;
                    if (n < N) {
                        const float bn = bias[n];
                        #pragma unroll
                        for (int i = 0; i < 8; ++i) {
                            const int lm = (i < 4) ? (tm * 4 + i) : (64 + tm * 4 + (i - 4));
                            float v = acc[i][j] + bn;
                            if (ACT == 1) v = fast_tanh(v);
                            else if (ACT == 2) v = __expf(v);
                            As[ln & 15][lm] = v;
                        }
                    }
                }
            }
            __syncthreads();
            #pragma unroll
            for (int p = 0; p < 2; ++p) {
                const int r = (tid >> 5) + p * 8;
                const int c = (tid & 31) * 4;
                const int n = n0 + chunk * 16 + r;
                if (n < N) {
                    *(float4*)&Cb[(size_t)n * T_DIM + c] = *(const float4*)&As[r][c];
                }
            }
        }
    }
}

#define PIN4(v) asm volatile("" : "+v"((v).x), "+v"((v).y), "+v"((v).z), "+v"((v).w))

// Backward LSTM: one block per batch row b, 512 threads (8 waves).
// Thread (wave w, lane l): h-index j = w*16 + (l&15), K-quarter kq = l>>4.
// Per-thread weights: 4 gates x 32 K-elems = 128 VGPRs, re-PINned at the
// bottom of every t-iteration (loop-carried asm dependence) so the compiler
// cannot re-materialize them inside the loop.
// Cross-kq combine: shfl_xor 16 + 32 (in-wave). Double-buffered LDS h, ONE
// barrier per step. gin layout [B,T,512] (biases folded), g_out [B,T,128].
__global__ __launch_bounds__(512, 2) void lstm_kernel(
    const float* __restrict__ gin,
    const float* __restrict__ W_hh,   // [512,128] row-major
    float* __restrict__ g_out)
{
    __shared__ float hbuf[2][128];
    const int tid  = threadIdx.x;
    const int b    = blockIdx.x;
    const int lane = tid & 63;
    const int w    = tid >> 6;             // wave 0..7
    const int j    = w * 16 + (lane & 15); // h index 0..127
    const int kq   = lane >> 4;            // K-quarter 0..3

    // weights: rows j, j+128, j+256, j+384, float4 cols [kq*8, kq*8+8)
    float4 wi[8], wf[8], wg[8], wo[8];
    {
        const float4* w4 = (const float4*)W_hh;
        const int cb = kq * 8;
        #pragma unroll
        for (int q = 0; q < 8; ++q) {
            wi[q] = w4[(size_t)(j      ) * 32 + cb + q];
            wf[q] = w4[(size_t)(j + 128) * 32 + cb + q];
            wg[q] = w4[(size_t)(j + 256) * 32 + cb + q];
            wo[q] = w4[(size_t)(j + 384) * 32 + cb + q];
        }
        #pragma unroll
        for (int q = 0; q < 8; ++q) { PIN4(wi[q]); PIN4(wf[q]); PIN4(wg[q]); PIN4(wo[q]); }
    }
    if (tid < 128) { hbuf[0][tid] = 0.f; hbuf[1][tid] = 0.f; }
    float c = 0.0f;
    __syncthreads();

    const float* ginb = gin + (size_t)b * T_DIM * G4;
    float gi = ginb[(size_t)(T_DIM - 1) * G4 + j];
    float gf = ginb[(size_t)(T_DIM - 1) * G4 + j + 128];
    float gg = ginb[(size_t)(T_DIM - 1) * G4 + j + 256];
    float go = ginb[(size_t)(T_DIM - 1) * G4 + j + 384];

    int buf = 0;
    for (int t = T_DIM - 1; t >= 0; --t) {
        float ngi = 0.f, ngf = 0.f, ngg = 0.f, ngo = 0.f;
        if (t > 0) {
            const size_t base = (size_t)(t - 1) * G4;
            ngi = ginb[base + j];
            ngf = ginb[base + j + 128];
            ngg = ginb[base + j + 256];
            ngo = ginb[base + j + 384];
        }
        float si = 0.f, sf = 0.f, sg = 0.f, so = 0.f;
        {
            const float4* h4 = (const float4*)&hbuf[buf][kq * 32];
            #pragma unroll
            for (int q = 0; q < 8; ++q) {
                const float4 hv = h4[q];
                si += wi[q].x * hv.x + wi[q].y * hv.y + wi[q].z * hv.z + wi[q].w * hv.w;
                sf += wf[q].x * hv.x + wf[q].y * hv.y + wf[q].z * hv.z + wf[q].w * hv.w;
                sg += wg[q].x * hv.x + wg[q].y * hv.y + wg[q].z * hv.z + wg[q].w * hv.w;
                so += wo[q].x * hv.x + wo[q].y * hv.y + wo[q].z * hv.z + wo[q].w * hv.w;
            }
        }
        si += __shfl_xor(si, 16, 64); si += __shfl_xor(si, 32, 64);
        sf += __shfl_xor(sf, 16, 64); sf += __shfl_xor(sf, 32, 64);
        sg += __shfl_xor(sg, 16, 64); sg += __shfl_xor(sg, 32, 64);
        so += __shfl_xor(so, 16, 64); so += __shfl_xor(so, 32, 64);
        si += gi; sf += gf; sg += gg; so += go;
        c = fast_sig(sf) * c + fast_sig(si) * fast_tanh(sg);
        const float h = fast_sig(so) * fast_tanh(c);
        buf ^= 1;
        if (kq == 0) {
            hbuf[buf][j] = h;
            g_out[((size_t)b * T_DIM + t) * H_DIM + j] = h;
        }
        __syncthreads();
        gi = ngi; gf = ngf; gg = ngg; go = ngo;
        // Loop-carried pin: weights must cross the back-edge in VGPRs.
        #pragma unroll
        for (int q = 0; q < 8; ++q) { PIN4(wi[q]); PIN4(wf[q]); PIN4(wg[q]); PIN4(wo[q]); }
    }
}

// Inference scan: one block (1 wave, 64 lanes) per batch row. All weights in registers.
// g layout [B,T,128], eps layout [T,B,16], z_out layout [B,T,16].
__global__ __launch_bounds__(64, 1) void infer_kernel(
    const float* __restrict__ g,
    const float* __restrict__ eps,
    const float* __restrict__ W_zg0, const float* __restrict__ b_zg0,
    const float* __restrict__ W_zg1, const float* __restrict__ b_zg1,
    const float* __restrict__ W_im,  const float* __restrict__ b_im,
    const float* __restrict__ W_il,  const float* __restrict__ b_il,
    float* __restrict__ z_out)
{
    __shared__ float zbuf[16];
    __shared__ float hzbuf[32];
    __shared__ float h2buf[128];
    const int l = threadIdx.x;
    const int b = blockIdx.x;

    // stage-1 weights: W_zg0 row (l&31), 16 wide
    const int r0 = l & 31;
    float4 wz0[4];
    #pragma unroll
    for (int q = 0; q < 4; ++q) wz0[q] = ((const float4*)W_zg0)[r0 * 4 + q];
    const float bz0 = b_zg0[r0];
    // stage-2 weights: W_zg1 rows l and l+64, 32 wide each
    float4 w1a[8], w1b[8];
    #pragma unroll
    for (int q = 0; q < 8; ++q) {
        w1a[q] = ((const float4*)W_zg1)[l * 8 + q];
        w1b[q] = ((const float4*)W_zg1)[(l + 64) * 8 + q];
    }
    const float bz1a = b_zg1[l], bz1b = b_zg1[l + 64];
    // stage-3 weights: output o=l&31 (o<16: zm row o; else zl row o-16), k half = l>>5
    const int o = l & 31;
    const int half = l >> 5;
    const float* w3p = (o < 16) ? (W_im + o * 128) : (W_il + (o - 16) * 128);
    float4 w3[16];
    #pragma unroll
    for (int q = 0; q < 16; ++q) w3[q] = ((const float4*)(w3p + half * 64))[q];
    const float b3 = (o < 16) ? b_im[o] : b_il[o - 16];

    if (l < 16) zbuf[l] = 0.0f;
    __syncthreads();

    const float* gb = g + (size_t)b * T_DIM * 128;
    float ngl0 = gb[l];
    float ngl1 = gb[64 + l];
    float neps = (l < 16) ? eps[(size_t)b * 16 + l] : 0.0f;
    for (int t = 0; t < T_DIM; ++t) {
        const float gl0 = ngl0, gl1 = ngl1, epsv = neps;
        if (t + 1 < T_DIM) {
            ngl0 = gb[(size_t)(t + 1) * 128 + l];
            ngl1 = gb[(size_t)(t + 1) * 128 + 64 + l];
            neps = (l < 16) ? eps[((size_t)(t + 1) * B_DIM + b) * 16 + l] : 0.0f;
        }
        // stage 1: hz = tanh(W_zg0 @ z + b_zg0), lanes 0..31
        float s1 = bz0;
        {
            const float4* z4 = (const float4*)zbuf;
            #pragma unroll
            for (int q = 0; q < 4; ++q) {
                const float4 zv = z4[q];
                s1 += wz0[q].x * zv.x + wz0[q].y * zv.y + wz0[q].z * zv.z + wz0[q].w * zv.w;
            }
        }
        const float hz = fast_tanh(s1);
        __syncthreads();
        if (l < 32) hzbuf[l] = hz;
        __syncthreads();
        // stage 2: hz2 = tanh(W_zg1 @ hz + b_zg1); g_t = 0.5*(hz2 + g_rnn)
        float s2a = bz1a, s2b = bz1b;
        {
            const float4* hz4 = (const float4*)hzbuf;
            #pragma unroll
            for (int q = 0; q < 8; ++q) {
                const float4 hv = hz4[q];
                s2a += w1a[q].x * hv.x + w1a[q].y * hv.y + w1a[q].z * hv.z + w1a[q].w * hv.w;
                s2b += w1b[q].x * hv.x + w1b[q].y * hv.y + w1b[q].z * hv.z + w1b[q].w * hv.w;
            }
        }
        const float gt0 = 0.5f * (fast_tanh(s2a) + gl0);
        const float gt1 = 0.5f * (fast_tanh(s2b) + gl1);
        __syncthreads();
        h2buf[l]      = gt0;
        h2buf[l + 64] = gt1;
        __syncthreads();
        // stage 3: zm/zl dot-128, split over lane pairs (l, l^32), outputs o=l&31
        float s3 = 0.0f;
        {
            const float4* h24 = (const float4*)(h2buf + half * 64);
            #pragma unroll
            for (int q = 0; q < 16; ++q) {
                const float4 hv = h24[q];
                s3 += w3[q].x * hv.x + w3[q].y * hv.y + w3[q].z * hv.z + w3[q].w * hv.w;
            }
        }
        const float full = s3 + __shfl_xor(s3, 32, 64);
        const float val = full + b3;                 // o<16: zm[o], o>=16: zl[o-16]
        const float other = __shfl_xor(val, 16, 64); // for l<16: zl[l]
        const float znew = val + epsv * __expf(0.5f * other);
        __syncthreads();
        if (l < 16) {
            zbuf[l] = znew;
            z_out[((size_t)b * T_DIM + t) * 16 + l] = znew;
        }
        __syncthreads();
    }
}

extern "C" void kernel_launch(void* const* d_in, const int* in_sizes, int n_in,
                              void* d_out, int out_size, void* d_ws, size_t ws_size,
                              hipStream_t stream)
{
    const float* x     = (const float*)d_in[0];
    const float* eps   = (const float*)d_in[1];
    const float* W_xg  = (const float*)d_in[2];
    const float* b_xg  = (const float*)d_in[3];
    const float* W_ih  = (const float*)d_in[4];
    const float* W_hh  = (const float*)d_in[5];
    const float* b_ih  = (const float*)d_in[6];
    const float* b_hh  = (const float*)d_in[7];
    const float* W_zg0 = (const float*)d_in[8];
    const float* b_zg0 = (const float*)d_in[9];
    const float* W_zg1 = (const float*)d_in[10];
    const float* b_zg1 = (const float*)d_in[11];
    const float* W_im  = (const float*)d_in[12];
    const float* b_im  = (const float*)d_in[13];
    const float* W_il  = (const float*)d_in[14];
    const float* b_il  = (const float*)d_in[15];
    // 16..27: gate/prop/pm/pl weights — dead code (outputs unused by reference return)
    const float* W_zx0 = (const float*)d_in[28];
    const float* b_zx0 = (const float*)d_in[29];
    const float* W_zx1 = (const float*)d_in[30];
    const float* b_zx1 = (const float*)d_in[31];
    const float* W_gy  = (const float*)d_in[32];
    const float* b_gy  = (const float*)d_in[33];
    float* out = (float*)d_out;
    float* ws  = (float*)d_ws;

    // workspace layout (floats)
    float* xg  = ws;                        // 131072*256 = 33,554,432
    float* gin = ws + 33554432ull;          // 131072*512 = 67,108,864
    float* g   = ws + 100663296ull;         // 131072*128 = 16,777,216
    float* z   = ws + 117440512ull;         // 131072*16  =  2,097,152
    float* bc  = ws + 119537664ull;         // 512
    float* hy1 = ws;                        // alias xg (dead after G2)
    float* hy2 = ws + 16777216ull;          // alias xg upper half

    bias_comb_kernel<<<1, 512, 0, stream>>>(b_ih, b_hh, bc);
    // G1: xg = tanh(xs @ W_xg.T + b_xg), m = b*T+t, A = x gather, K=513
    gemm_kernel<1, 1, 0, true><<<dim3(DX / 128, M_ROWS / 128), 256, 0, stream>>>(
        x, W_xg, b_xg, xg, M_ROWS, DX, F_DIM);
    // G2: gin = xg @ W_ih.T + (b_ih + b_hh), K=256, N=512
    gemm_kernel<0, 0, 0, false><<<dim3(G4 / 128, M_ROWS / 128), 256, 0, stream>>>(
        xg, W_ih, bc, gin, M_ROWS, G4, DX);
    // backward LSTM scan -> g
    lstm_kernel<<<B_DIM, 512, 0, stream>>>(gin, W_hh, g);
    // inference scan -> z
    infer_kernel<<<B_DIM, 64, 0, stream>>>(g, eps, W_zg0, b_zg0, W_zg1, b_zg1,
                                           W_im, b_im, W_il, b_il, z);
    // y path
    gemm_kernel<1, 0, 0, false><<<dim3(DZX_D / 128, M_ROWS / 128), 256, 0, stream>>>(
        z, W_zx0, b_zx0, hy1, M_ROWS, DZX_D, Z_DIM);
    gemm_kernel<1, 0, 0, false><<<dim3(DZX_D / 128, M_ROWS / 128), 256, 0, stream>>>(
        hy1, W_zx1, b_zx1, hy2, M_ROWS, DZX_D, DZX_D);
    gemm_kernel<2, 0, 1, true><<<dim3(5, M_ROWS / 128), 256, 0, stream>>>(
        hy2, W_gy, b_gy, out, M_ROWS, F_DIM, DZX_D);
}

// Round 5
// 2988.088 us; speedup vs baseline: 6.2186x; 6.2186x over previous
//
#include <hip/hip_runtime.h>
#include <cstdint>

#define T_DIM 512
#define B_DIM 256
#define F_DIM 513
#define DX    256
#define H_DIM 128
#define G4    512
#define Z_DIM 16
#define ZG_D  32
#define DZX_D 128
#define M_ROWS (B_DIM * T_DIM)   // 131072

__device__ __forceinline__ float fast_tanh(float x) {
    return 1.0f - 2.0f / (__expf(2.0f * x) + 1.0f);
}
__device__ __forceinline__ float fast_sig(float x) {
    return 1.0f / (1.0f + __expf(-x));
}

__global__ void bias_comb_kernel(const float* __restrict__ a,
                                 const float* __restrict__ b,
                                 float* __restrict__ c) {
    int i = threadIdx.x;
    if (i < G4) c[i] = a[i] + b[i];
}

// ---- GEMM staging macros (SCALARS ONLY — round-4 lesson: arrays captured by
// lambda reference lose SROA, land in scratch, and drag the accumulator into
// spills with them: VGPR 84, 13.5 GB scratch writes, VALUBusy 6%). ----
#define GEMM_STAGE(kt_) do {                                                   \
    const int k0s_ = (kt_) << 4;                                               \
    if (AMODE == 0) {                                                          \
        const float* ap_ = &A[(size_t)(m0 + (tid >> 1)) * K + k0s_ + (tid & 1) * 8]; \
        const float4 v0_ = *(const float4*)(ap_);                              \
        const float4 v1_ = *(const float4*)(ap_ + 4);                          \
        sa0 = v0_.x; sa1 = v0_.y; sa2 = v0_.z; sa3 = v0_.w;                    \
        sa4 = v1_.x; sa5 = v1_.y; sa6 = v1_.z; sa7 = v1_.w;                    \
    } else {                                                                   \
        const int mg_ = m0 + (tid & 127);                                      \
        const size_t base_ = (size_t)(mg_ >> 9) * (F_DIM * T_DIM) + (mg_ & 511); \
        const int kb_ = k0s_ + (tid >> 7) * 8;                                 \
        sa0 = (kb_ + 0 < K) ? A[base_ + (size_t)(kb_ + 0) * T_DIM] : 0.0f;     \
        sa1 = (kb_ + 1 < K) ? A[base_ + (size_t)(kb_ + 1) * T_DIM] : 0.0f;     \
        sa2 = (kb_ + 2 < K) ? A[base_ + (size_t)(kb_ + 2) * T_DIM] : 0.0f;     \
        sa3 = (kb_ + 3 < K) ? A[base_ + (size_t)(kb_ + 3) * T_DIM] : 0.0f;     \
        sa4 = (kb_ + 4 < K) ? A[base_ + (size_t)(kb_ + 4) * T_DIM] : 0.0f;     \
        sa5 = (kb_ + 5 < K) ? A[base_ + (size_t)(kb_ + 5) * T_DIM] : 0.0f;     \
        sa6 = (kb_ + 6 < K) ? A[base_ + (size_t)(kb_ + 6) * T_DIM] : 0.0f;     \
        sa7 = (kb_ + 7 < K) ? A[base_ + (size_t)(kb_ + 7) * T_DIM] : 0.0f;     \
    }                                                                          \
    {                                                                          \
        const int ng_ = n0 + (tid >> 1);                                       \
        const int kb_ = k0s_ + (tid & 1) * 8;                                  \
        if (!GUARD) {                                                          \
            const float* wp_ = &W[(size_t)ng_ * K + kb_];                      \
            const float4 v0_ = *(const float4*)(wp_);                          \
            const float4 v1_ = *(const float4*)(wp_ + 4);                      \
            sb0 = v0_.x; sb1 = v0_.y; sb2 = v0_.z; sb3 = v0_.w;                \
            sb4 = v1_.x; sb5 = v1_.y; sb6 = v1_.z; sb7 = v1_.w;                \
        } else {                                                               \
            const size_t wb_ = (size_t)ng_ * K;                                \
            const bool okn_ = (ng_ < N);                                       \
            sb0 = (okn_ && kb_ + 0 < K) ? W[wb_ + kb_ + 0] : 0.0f;             \
            sb1 = (okn_ && kb_ + 1 < K) ? W[wb_ + kb_ + 1] : 0.0f;             \
            sb2 = (okn_ && kb_ + 2 < K) ? W[wb_ + kb_ + 2] : 0.0f;             \
            sb3 = (okn_ && kb_ + 3 < K) ? W[wb_ + kb_ + 3] : 0.0f;             \
            sb4 = (okn_ && kb_ + 4 < K) ? W[wb_ + kb_ + 4] : 0.0f;             \
            sb5 = (okn_ && kb_ + 5 < K) ? W[wb_ + kb_ + 5] : 0.0f;             \
            sb6 = (okn_ && kb_ + 6 < K) ? W[wb_ + kb_ + 6] : 0.0f;             \
            sb7 = (okn_ && kb_ + 7 < K) ? W[wb_ + kb_ + 7] : 0.0f;             \
        }                                                                      \
    }                                                                          \
} while (0)

#define GEMM_COMMIT(bi_) do {                                                  \
    const int ma_ = (AMODE == 0) ? (tid >> 1) : (tid & 127);                   \
    const int ka_ = ((AMODE == 0) ? (tid & 1) : (tid >> 7)) * 8;               \
    As[bi_][ka_ + 0][ma_] = sa0; As[bi_][ka_ + 1][ma_] = sa1;                  \
    As[bi_][ka_ + 2][ma_] = sa2; As[bi_][ka_ + 3][ma_] = sa3;                  \
    As[bi_][ka_ + 4][ma_] = sa4; As[bi_][ka_ + 5][ma_] = sa5;                  \
    As[bi_][ka_ + 6][ma_] = sa6; As[bi_][ka_ + 7][ma_] = sa7;                  \
    const int nb_ = tid >> 1;                                                  \
    const int kc_ = (tid & 1) * 8;                                             \
    Bs[bi_][kc_ + 0][nb_] = sb0; Bs[bi_][kc_ + 1][nb_] = sb1;                  \
    Bs[bi_][kc_ + 2][nb_] = sb2; Bs[bi_][kc_ + 3][nb_] = sb3;                  \
    Bs[bi_][kc_ + 4][nb_] = sb4; Bs[bi_][kc_ + 5][nb_] = sb5;                  \
    Bs[bi_][kc_ + 6][nb_] = sb6; Bs[bi_][kc_ + 7][nb_] = sb7;                  \
} while (0)

// Generic tiled fp32 GEMM:  C[m,n] = act(sum_k A[m,k] * W[n,k] + bias[n])
// 128x128 tile, 256 threads, 8x8 per thread in a 2x2-of-4 split layout.
// Round-5: LDS DOUBLE buffer, ONE barrier per tile. Per iteration: stage
// tile kt+1 (clamped) into scalars -> compute tile kt from buf[cur] ->
// commit scalars into buf[cur^1] (disjoint from readers) -> barrier.
// Global-load latency hides under the 1024-FMA phase (loads' only users,
// the ds_writes, come after the FMAs; commit unconditional so nothing gets
// sunk into a branch). Round-3 counters showed VALUBusy 38% / occupancy 31%
// / HBM 6% -> latency-bound on the old sync->load->sync->compute chain.
// ACT: 0 none, 1 tanh, 2 exp
// AMODE: 0 contiguous row-major [M,K], 1 x-gather A[m,k]=x[b,k,t], m=b*T+t
// CMODE: 0 contiguous [M,N] (N%128==0), 1 transposed out[b,n,t] via LDS
//        re-tile (coalesced 512B row stores), n<N guard
// GUARD: scalar+bounds-guarded W loads (K edge or N edge)
template<int ACT, int AMODE, int CMODE, bool GUARD>
__global__ __launch_bounds__(256, 3) void gemm_kernel(
    const float* __restrict__ A, const float* __restrict__ W,
    const float* __restrict__ bias, float* __restrict__ C,
    int M, int N, int K)
{
    __shared__ float As[2][16][136];
    __shared__ float Bs[2][16][136];
    const int tid = threadIdx.x;
    const int m0 = blockIdx.y * 128;
    const int n0 = blockIdx.x * 128;
    const int tm = tid >> 4;   // 0..15
    const int tn = tid & 15;   // 0..15
    float acc[8][8] = {};
    const int kTiles = (K + 15) >> 4;

    float sa0, sa1, sa2, sa3, sa4, sa5, sa6, sa7;
    float sb0, sb1, sb2, sb3, sb4, sb5, sb6, sb7;

    GEMM_STAGE(0);
    GEMM_COMMIT(0);
    __syncthreads();
    int cur = 0;
    for (int kt = 0; kt < kTiles; ++kt) {
        const int ktn = (kt + 1 < kTiles) ? (kt + 1) : kt;  // clamped prefetch
        GEMM_STAGE(ktn);
        #pragma unroll
        for (int kk = 0; kk < 16; ++kk) {
            const float4 a0 = *(const float4*)&As[cur][kk][tm * 4];
            const float4 a1 = *(const float4*)&As[cur][kk][tm * 4 + 64];
            const float4 b0 = *(const float4*)&Bs[cur][kk][tn * 4];
            const float4 b1 = *(const float4*)&Bs[cur][kk][tn * 4 + 64];
            const float a[8] = { a0.x, a0.y, a0.z, a0.w, a1.x, a1.y, a1.z, a1.w };
            const float b[8] = { b0.x, b0.y, b0.z, b0.w, b1.x, b1.y, b1.z, b1.w };
            #pragma unroll
            for (int i = 0; i < 8; ++i)
                #pragma unroll
                for (int j = 0; j < 8; ++j)
                    acc[i][j] += a[i] * b[j];
        }
        GEMM_COMMIT(cur ^ 1);   // unconditional: last tile writes dead buffer
        __syncthreads();
        cur ^= 1;
    }
    // ---- epilogue ----
    if (CMODE == 0) {
        #pragma unroll
        for (int i = 0; i < 8; ++i) {
            const int m = m0 + ((i < 4) ? (tm * 4 + i) : (tm * 4 + 64 + (i - 4)));
            float r0[4], r1[4];
            #pragma unroll
            for (int j = 0; j < 4; ++j) {
                const int na = n0 + tn * 4 + j;
                float v = acc[i][j] + bias[na];
                if (ACT == 1) v = fast_tanh(v);
                else if (ACT == 2) v = __expf(v);
                r0[j] = v;
                const int nb = n0 + 64 + tn * 4 + j;
                float u = acc[i][j + 4] + bias[nb];
                if (ACT == 1) u = fast_tanh(u);
                else if (ACT == 2) u = __expf(u);
                r1[j] = u;
            }
            *(float4*)&C[(size_t)m * N + n0 + tn * 4]      = make_float4(r0[0], r0[1], r0[2], r0[3]);
            *(float4*)&C[(size_t)m * N + n0 + 64 + tn * 4] = make_float4(r1[0], r1[1], r1[2], r1[3]);
        }
    } else {
        // Transposed out[b,n,t]: re-tile through LDS in 16-n-row chunks so
        // stores are 512B-contiguous rows (was a 16B/lane scatter).
        const int bb  = m0 >> 9;      // m-block lies in one b (m0%512 + 127 < 512)
        const int tt0 = m0 & 511;
        float* Cb = C + (size_t)bb * (F_DIM * T_DIM) + tt0;
        #pragma unroll
        for (int chunk = 0; chunk < 8; ++chunk) {
            __syncthreads();
            #pragma unroll
            for (int j = 0; j < 8; ++j) {
                const int ln = (j < 4) ? (tn * 4 + j) : (64 + tn * 4 + (j - 4));
                if ((ln >> 4) == chunk) {
                    const int n = n0 + ln;
                    if (n < N) {
                        const float bn = bias[n];
                        #pragma unroll
                        for (int i = 0; i < 8; ++i) {
                            const int lm = (i < 4) ? (tm * 4 + i) : (64 + tm * 4 + (i - 4));
                            float v = acc[i][j] + bn;
                            if (ACT == 1) v = fast_tanh(v);
                            else if (ACT == 2) v = __expf(v);
                            As[0][ln & 15][lm] = v;
                        }
                    }
                }
            }
            __syncthreads();
            #pragma unroll
            for (int p = 0; p < 2; ++p) {
                const int r = (tid >> 5) + p * 8;
                const int c = (tid & 31) * 4;
                const int n = n0 + chunk * 16 + r;
                if (n < N) {
                    *(float4*)&Cb[(size_t)n * T_DIM + c] = *(const float4*)&As[0][r][c];
                }
            }
        }
    }
}

#define PIN4(v) asm volatile("" : "+v"((v).x), "+v"((v).y), "+v"((v).z), "+v"((v).w))

// Backward LSTM: one block per batch row b, 512 threads (8 waves).
// Thread (wave w, lane l): h-index j = w*16 + (l&15), K-quarter kq = l>>4.
// Per-thread weights: 4 gates x 32 K-elems = 128 VGPRs, re-PINned at the
// bottom of every t-iteration (loop-carried asm dependence) so the compiler
// cannot re-materialize them inside the loop.
// Cross-kq combine: shfl_xor 16 + 32 (in-wave). Double-buffered LDS h, ONE
// barrier per step. gin layout [B,T,512] (biases folded), g_out [B,T,128].
__global__ __launch_bounds__(512, 2) void lstm_kernel(
    const float* __restrict__ gin,
    const float* __restrict__ W_hh,   // [512,128] row-major
    float* __restrict__ g_out)
{
    __shared__ float hbuf[2][128];
    const int tid  = threadIdx.x;
    const int b    = blockIdx.x;
    const int lane = tid & 63;
    const int w    = tid >> 6;             // wave 0..7
    const int j    = w * 16 + (lane & 15); // h index 0..127
    const int kq   = lane >> 4;            // K-quarter 0..3

    // weights: rows j, j+128, j+256, j+384, float4 cols [kq*8, kq*8+8)
    float4 wi[8], wf[8], wg[8], wo[8];
    {
        const float4* w4 = (const float4*)W_hh;
        const int cb = kq * 8;
        #pragma unroll
        for (int q = 0; q < 8; ++q) {
            wi[q] = w4[(size_t)(j      ) * 32 + cb + q];
            wf[q] = w4[(size_t)(j + 128) * 32 + cb + q];
            wg[q] = w4[(size_t)(j + 256) * 32 + cb + q];
            wo[q] = w4[(size_t)(j + 384) * 32 + cb + q];
        }
        #pragma unroll
        for (int q = 0; q < 8; ++q) { PIN4(wi[q]); PIN4(wf[q]); PIN4(wg[q]); PIN4(wo[q]); }
    }
    if (tid < 128) { hbuf[0][tid] = 0.f; hbuf[1][tid] = 0.f; }
    float c = 0.0f;
    __syncthreads();

    const float* ginb = gin + (size_t)b * T_DIM * G4;
    float gi = ginb[(size_t)(T_DIM - 1) * G4 + j];
    float gf = ginb[(size_t)(T_DIM - 1) * G4 + j + 128];
    float gg = ginb[(size_t)(T_DIM - 1) * G4 + j + 256];
    float go = ginb[(size_t)(T_DIM - 1) * G4 + j + 384];

    int buf = 0;
    for (int t = T_DIM - 1; t >= 0; --t) {
        float ngi = 0.f, ngf = 0.f, ngg = 0.f, ngo = 0.f;
        if (t > 0) {
            const size_t base = (size_t)(t - 1) * G4;
            ngi = ginb[base + j];
            ngf = ginb[base + j + 128];
            ngg = ginb[base + j + 256];
            ngo = ginb[base + j + 384];
        }
        float si = 0.f, sf = 0.f, sg = 0.f, so = 0.f;
        {
            const float4* h4 = (const float4*)&hbuf[buf][kq * 32];
            #pragma unroll
            for (int q = 0; q < 8; ++q) {
                const float4 hv = h4[q];
                si += wi[q].x * hv.x + wi[q].y * hv.y + wi[q].z * hv.z + wi[q].w * hv.w;
                sf += wf[q].x * hv.x + wf[q].y * hv.y + wf[q].z * hv.z + wf[q].w * hv.w;
                sg += wg[q].x * hv.x + wg[q].y * hv.y + wg[q].z * hv.z + wg[q].w * hv.w;
                so += wo[q].x * hv.x + wo[q].y * hv.y + wo[q].z * hv.z + wo[q].w * hv.w;
            }
        }
        si += __shfl_xor(si, 16, 64); si += __shfl_xor(si, 32, 64);
        sf += __shfl_xor(sf, 16, 64); sf += __shfl_xor(sf, 32, 64);
        sg += __shfl_xor(sg, 16, 64); sg += __shfl_xor(sg, 32, 64);
        so += __shfl_xor(so, 16, 64); so += __shfl_xor(so, 32, 64);
        si += gi; sf += gf; sg += gg; so += go;
        c = fast_sig(sf) * c + fast_sig(si) * fast_tanh(sg);
        const float h = fast_sig(so) * fast_tanh(c);
        buf ^= 1;
        if (kq == 0) {
            hbuf[buf][j] = h;
            g_out[((size_t)b * T_DIM + t) * H_DIM + j] = h;
        }
        __syncthreads();
        gi = ngi; gf = ngf; gg = ngg; go = ngo;
        // Loop-carried pin: weights must cross the back-edge in VGPRs.
        #pragma unroll
        for (int q = 0; q < 8; ++q) { PIN4(wi[q]); PIN4(wf[q]); PIN4(wg[q]); PIN4(wo[q]); }
    }
}

// Inference scan: one block (1 wave, 64 lanes) per batch row. All weights in registers.
// g layout [B,T,128], eps layout [T,B,16], z_out layout [B,T,16].
__global__ __launch_bounds__(64, 1) void infer_kernel(
    const float* __restrict__ g,
    const float* __restrict__ eps,
    const float* __restrict__ W_zg0, const float* __restrict__ b_zg0,
    const float* __restrict__ W_zg1, const float* __restrict__ b_zg1,
    const float* __restrict__ W_im,  const float* __restrict__ b_im,
    const float* __restrict__ W_il,  const float* __restrict__ b_il,
    float* __restrict__ z_out)
{
    __shared__ float zbuf[16];
    __shared__ float hzbuf[32];
    __shared__ float h2buf[128];
    const int l = threadIdx.x;
    const int b = blockIdx.x;

    // stage-1 weights: W_zg0 row (l&31), 16 wide
    const int r0 = l & 31;
    float4 wz0[4];
    #pragma unroll
    for (int q = 0; q < 4; ++q) wz0[q] = ((const float4*)W_zg0)[r0 * 4 + q];
    const float bz0 = b_zg0[r0];
    // stage-2 weights: W_zg1 rows l and l+64, 32 wide each
    float4 w1a[8], w1b[8];
    #pragma unroll
    for (int q = 0; q < 8; ++q) {
        w1a[q] = ((const float4*)W_zg1)[l * 8 + q];
        w1b[q] = ((const float4*)W_zg1)[(l + 64) * 8 + q];
    }
    const float bz1a = b_zg1[l], bz1b = b_zg1[l + 64];
    // stage-3 weights: output o=l&31 (o<16: zm row o; else zl row o-16), k half = l>>5
    const int o = l & 31;
    const int half = l >> 5;
    const float* w3p = (o < 16) ? (W_im + o * 128) : (W_il + (o - 16) * 128);
    float4 w3[16];
    #pragma unroll
    for (int q = 0; q < 16; ++q) w3[q] = ((const float4*)(w3p + half * 64))[q];
    const float b3 = (o < 16) ? b_im[o] : b_il[o - 16];

    if (l < 16) zbuf[l] = 0.0f;
    __syncthreads();

    const float* gb = g + (size_t)b * T_DIM * 128;
    float ngl0 = gb[l];
    float ngl1 = gb[64 + l];
    float neps = (l < 16) ? eps[(size_t)b * 16 + l] : 0.0f;
    for (int t = 0; t < T_DIM; ++t) {
        const float gl0 = ngl0, gl1 = ngl1, epsv = neps;
        if (t + 1 < T_DIM) {
            ngl0 = gb[(size_t)(t + 1) * 128 + l];
            ngl1 = gb[(size_t)(t + 1) * 128 + 64 + l];
            neps = (l < 16) ? eps[((size_t)(t + 1) * B_DIM + b) * 16 + l] : 0.0f;
        }
        // stage 1: hz = tanh(W_zg0 @ z + b_zg0), lanes 0..31
        float s1 = bz0;
        {
            const float4* z4 = (const float4*)zbuf;
            #pragma unroll
            for (int q = 0; q < 4; ++q) {
                const float4 zv = z4[q];
                s1 += wz0[q].x * zv.x + wz0[q].y * zv.y + wz0[q].z * zv.z + wz0[q].w * zv.w;
            }
        }
        const float hz = fast_tanh(s1);
        __syncthreads();
        if (l < 32) hzbuf[l] = hz;
        __syncthreads();
        // stage 2: hz2 = tanh(W_zg1 @ hz + b_zg1); g_t = 0.5*(hz2 + g_rnn)
        float s2a = bz1a, s2b = bz1b;
        {
            const float4* hz4 = (const float4*)hzbuf;
            #pragma unroll
            for (int q = 0; q < 8; ++q) {
                const float4 hv = hz4[q];
                s2a += w1a[q].x * hv.x + w1a[q].y * hv.y + w1a[q].z * hv.z + w1a[q].w * hv.w;
                s2b += w1b[q].x * hv.x + w1b[q].y * hv.y + w1b[q].z * hv.z + w1b[q].w * hv.w;
            }
        }
        const float gt0 = 0.5f * (fast_tanh(s2a) + gl0);
        const float gt1 = 0.5f * (fast_tanh(s2b) + gl1);
        __syncthreads();
        h2buf[l]      = gt0;
        h2buf[l + 64] = gt1;
        __syncthreads();
        // stage 3: zm/zl dot-128, split over lane pairs (l, l^32), outputs o=l&31
        float s3 = 0.0f;
        {
            const float4* h24 = (const float4*)(h2buf + half * 64);
            #pragma unroll
            for (int q = 0; q < 16; ++q) {
                const float4 hv = h24[q];
                s3 += w3[q].x * hv.x + w3[q].y * hv.y + w3[q].z * hv.z + w3[q].w * hv.w;
            }
        }
        const float full = s3 + __shfl_xor(s3, 32, 64);
        const float val = full + b3;                 // o<16: zm[o], o>=16: zl[o-16]
        const float other = __shfl_xor(val, 16, 64); // for l<16: zl[l]
        const float znew = val + epsv * __expf(0.5f * other);
        __syncthreads();
        if (l < 16) {
            zbuf[l] = znew;
            z_out[((size_t)b * T_DIM + t) * 16 + l] = znew;
        }
        __syncthreads();
    }
}

extern "C" void kernel_launch(void* const* d_in, const int* in_sizes, int n_in,
                              void* d_out, int out_size, void* d_ws, size_t ws_size,
                              hipStream_t stream)
{
    const float* x     = (const float*)d_in[0];
    const float* eps   = (const float*)d_in[1];
    const float* W_xg  = (const float*)d_in[2];
    const float* b_xg  = (const float*)d_in[3];
    const float* W_ih  = (const float*)d_in[4];
    const float* W_hh  = (const float*)d_in[5];
    const float* b_ih  = (const float*)d_in[6];
    const float* b_hh  = (const float*)d_in[7];
    const float* W_zg0 = (const float*)d_in[8];
    const float* b_zg0 = (const float*)d_in[9];
    const float* W_zg1 = (const float*)d_in[10];
    const float* b_zg1 = (const float*)d_in[11];
    const float* W_im  = (const float*)d_in[12];
    const float* b_im  = (const float*)d_in[13];
    const float* W_il  = (const float*)d_in[14];
    const float* b_il  = (const float*)d_in[15];
    // 16..27: gate/prop/pm/pl weights — dead code (outputs unused by reference return)
    const float* W_zx0 = (const float*)d_in[28];
    const float* b_zx0 = (const float*)d_in[29];
    const float* W_zx1 = (const float*)d_in[30];
    const float* b_zx1 = (const float*)d_in[31];
    const float* W_gy  = (const float*)d_in[32];
    const float* b_gy  = (const float*)d_in[33];
    float* out = (float*)d_out;
    float* ws  = (float*)d_ws;

    // workspace layout (floats)
    float* xg  = ws;                        // 131072*256 = 33,554,432
    float* gin = ws + 33554432ull;          // 131072*512 = 67,108,864
    float* g   = ws + 100663296ull;         // 131072*128 = 16,777,216
    float* z   = ws + 117440512ull;         // 131072*16  =  2,097,152
    float* bc  = ws + 119537664ull;         // 512
    float* hy1 = ws;                        // alias xg (dead after G2)
    float* hy2 = ws + 16777216ull;          // alias xg upper half

    bias_comb_kernel<<<1, 512, 0, stream>>>(b_ih, b_hh, bc);
    // G1: xg = tanh(xs @ W_xg.T + b_xg), m = b*T+t, A = x gather, K=513
    gemm_kernel<1, 1, 0, true><<<dim3(DX / 128, M_ROWS / 128), 256, 0, stream>>>(
        x, W_xg, b_xg, xg, M_ROWS, DX, F_DIM);
    // G2: gin = xg @ W_ih.T + (b_ih + b_hh), K=256, N=512
    gemm_kernel<0, 0, 0, false><<<dim3(G4 / 128, M_ROWS / 128), 256, 0, stream>>>(
        xg, W_ih, bc, gin, M_ROWS, G4, DX);
    // backward LSTM scan -> g
    lstm_kernel<<<B_DIM, 512, 0, stream>>>(gin, W_hh, g);
    // inference scan -> z
    infer_kernel<<<B_DIM, 64, 0, stream>>>(g, eps, W_zg0, b_zg0, W_zg1, b_zg1,
                                           W_im, b_im, W_il, b_il, z);
    // y path
    gemm_kernel<1, 0, 0, false><<<dim3(DZX_D / 128, M_ROWS / 128), 256, 0, stream>>>(
        z, W_zx0, b_zx0, hy1, M_ROWS, DZX_D, Z_DIM);
    gemm_kernel<1, 0, 0, false><<<dim3(DZX_D / 128, M_ROWS / 128), 256, 0, stream>>>(
        hy1, W_zx1, b_zx1, hy2, M_ROWS, DZX_D, DZX_D);
    gemm_kernel<2, 0, 1, true><<<dim3(5, M_ROWS / 128), 256, 0, stream>>>(
        hy2, W_gy, b_gy, out, M_ROWS, F_DIM, DZX_D);
}